// Round 13
// baseline (32.770 us; speedup 1.0000x reference)
//
#include <hip/hip_runtime.h>
#include <hip/hip_bf16.h>
#include <math.h>

// Problem: B=16, K=256, D=128, H=64
//   sd[b,i,j] = sum_h gelu(hi[b,i,h] + hj[b,j,h]) * W2[h] + b2,  loss = MSE vs dist
//
// R10/R11 lessons (measured): f32 FLOP rate is fixed (1 fma/lane/cyc; pk = same);
// only op COUNT and pipe BALANCE matter. R12: gelu = Schraudolph exp (VALU,
// fma+cvt) + hardware v_rcp_f32 (trans pipe) -> 6 VALU + 1 trans per elem;
// VALU 12cyc vs trans 8cyc per wave-elem -> VALU-bound at 12 (was 18).
// kA: 512 blocks x 8 rows -> 2 blocks/CU (was 1, zero latency hiding).

#define Bn 16
#define Kn 256
#define Dn 128
#define Hn 64
#define NBLK 1024    // kB grid: 8 x 8 x 16
#define ROWS_A 8     // kA rows per block

// gelu(x) ~= x * sigmoid(1.702 x)
//   e = 2^(-2.4555 x) via Schraudolph bits = fma(x, -2.4555*2^23, (127-0.0436)*2^23)
//   r = v_rcp_f32(1 + e)   (trans pipe, ~1 ulp)
// 6 VALU (incl. caller's x-add) + 1 trans per element.
__device__ __forceinline__ void gelu_acc(float x, float w, float& acc) {
    float u  = fmaf(x, -20598733.0f, 1064987473.0f);
    int   iu = (int)u;                                   // u in (0, 2^31): |x| < 45
    float e  = __builtin_bit_cast(float, iu);
    float r  = __builtin_amdgcn_rcpf(e + 1.0f);
    acc = fmaf(x * r, w, acc);
}

// ---------------- Kernel A: hi/hj precompute ----------------
// 512 blocks x 256 threads; 8 rows/block. LDS 68 KB -> 2 blocks/CU.
// thread = (r = tid>>5, h0 = (tid&31)*2): 2 h-cols x {hi,hj}.
__global__ __launch_bounds__(256) void kA(const float* __restrict__ particles,
                                          const float* __restrict__ W1,
                                          const float* __restrict__ b1,
                                          float* __restrict__ hi,
                                          float* __restrict__ hj) {
    __shared__ __align__(16) float w1a[Dn * Hn];     // 32 KB  W1[:128]
    __shared__ __align__(16) float w1b[Dn * Hn];     // 32 KB  W1[128:]
    __shared__ __align__(16) float ps[ROWS_A][Dn];   // 4 KB
    __shared__ __align__(16) float b1s[Hn];

    const int tid = threadIdx.x;
    const int row0 = blockIdx.x * ROWS_A;

    for (int idx = tid; idx < (Dn * Hn) / 4; idx += 256) {
        ((float4*)w1a)[idx] = ((const float4*)W1)[idx];
        ((float4*)w1b)[idx] = ((const float4*)(W1 + Dn * Hn))[idx];
    }
    for (int idx = tid; idx < (ROWS_A * Dn) / 4; idx += 256)
        ((float4*)&ps[0][0])[idx] = ((const float4*)(particles + row0 * Dn))[idx];
    if (tid < Hn / 4)
        ((float4*)b1s)[tid] = ((const float4*)b1)[tid];
    __syncthreads();

    const int r  = tid >> 5;
    const int h0 = (tid & 31) * 2;

    float2 ai = {0.f, 0.f};
    float2 aj = {0.f, 0.f};
#pragma unroll 8
    for (int d = 0; d < Dn; ++d) {
        const float p  = ps[r][d];
        const float2 wa = *(const float2*)&w1a[d * Hn + h0];
        const float2 wb = *(const float2*)&w1b[d * Hn + h0];
        ai.x = fmaf(p, wa.x, ai.x); ai.y = fmaf(p, wa.y, ai.y);
        aj.x = fmaf(p, wb.x, aj.x); aj.y = fmaf(p, wb.y, aj.y);
    }
    const float2 bb = *(const float2*)&b1s[h0];
    ai.x += bb.x; ai.y += bb.y;

    *(float2*)&hi[(row0 + r) * Hn + h0] = ai;
    *(float2*)&hj[(row0 + r) * Hn + h0] = aj;
}

// ---------------- Kernel B: 32x32 tile, 4 outputs/thread ----------------
// grid (K/32, K/32, B) = (8,8,16), 256 threads. Thread (ti=tid>>4, tj=tid&15)
// computes (i0,j0) (i0,j1) (i1,j0) (i1,j1), i1=i0+16, j1=j0+16.
__global__ __launch_bounds__(256) void kB(const float* __restrict__ hi,
                                          const float* __restrict__ hj,
                                          const float* __restrict__ positions,
                                          const float* __restrict__ W2,
                                          const float* __restrict__ b2,
                                          float* __restrict__ out,
                                          float* __restrict__ partials) {
    __shared__ __align__(16) float shi[32][68];
    __shared__ __align__(16) float shj[32][68];
    __shared__ __align__(16) float w2s[Hn];
    __shared__ float pix[32], piy[32], pjx[32], pjy[32];
    __shared__ float wsum[4];

    const int jt = blockIdx.x, it = blockIdx.y, b = blockIdx.z;
    const int tid = threadIdx.x;
    const int bi = b * Kn + it * 32;
    const int bj = b * Kn + jt * 32;

    // stage: 512 float4 each for shi/shj (2 per thread)
    for (int idx = tid; idx < 512; idx += 256) {
        const int rr = idx >> 4, c4 = (idx & 15) * 4;
        *(float4*)&shi[rr][c4] = *(const float4*)&hi[(bi + rr) * Hn + c4];
        *(float4*)&shj[rr][c4] = *(const float4*)&hj[(bj + rr) * Hn + c4];
    }
    if (tid < Hn / 4)
        ((float4*)w2s)[tid] = ((const float4*)W2)[tid];
    if (tid < 32) {
        pix[tid] = positions[(bi + tid) * 2 + 0];
        piy[tid] = positions[(bi + tid) * 2 + 1];
        pjx[tid] = positions[(bj + tid) * 2 + 0];
        pjy[tid] = positions[(bj + tid) * 2 + 1];
    }
    const float bb = b2[0];
    __syncthreads();

    const int ti = tid >> 4, tj = tid & 15;

    float acc00 = 0.f, acc01 = 0.f, acc10 = 0.f, acc11 = 0.f;
#pragma unroll
    for (int h = 0; h < Hn; h += 4) {
        const float4 a0 = *(const float4*)&shi[ti][h];
        const float4 a1 = *(const float4*)&shi[ti + 16][h];
        const float4 c0 = *(const float4*)&shj[tj][h];
        const float4 c1 = *(const float4*)&shj[tj + 16][h];
        const float4 w  = *(const float4*)&w2s[h];
        gelu_acc(a0.x + c0.x, w.x, acc00); gelu_acc(a0.y + c0.y, w.y, acc00);
        gelu_acc(a0.z + c0.z, w.z, acc00); gelu_acc(a0.w + c0.w, w.w, acc00);
        gelu_acc(a0.x + c1.x, w.x, acc01); gelu_acc(a0.y + c1.y, w.y, acc01);
        gelu_acc(a0.z + c1.z, w.z, acc01); gelu_acc(a0.w + c1.w, w.w, acc01);
        gelu_acc(a1.x + c0.x, w.x, acc10); gelu_acc(a1.y + c0.y, w.y, acc10);
        gelu_acc(a1.z + c0.z, w.z, acc10); gelu_acc(a1.w + c0.w, w.w, acc10);
        gelu_acc(a1.x + c1.x, w.x, acc11); gelu_acc(a1.y + c1.y, w.y, acc11);
        gelu_acc(a1.z + c1.z, w.z, acc11); gelu_acc(a1.w + c1.w, w.w, acc11);
    }
    const float sd00 = acc00 + bb, sd01 = acc01 + bb;
    const float sd10 = acc10 + bb, sd11 = acc11 + bb;

    const float xi0 = pix[ti], yi0 = piy[ti], xi1 = pix[ti + 16], yi1 = piy[ti + 16];
    const float xj0 = pjx[tj], yj0 = pjy[tj], xj1 = pjx[tj + 16], yj1 = pjy[tj + 16];
    const float d200 = (xi0-xj0)*(xi0-xj0) + (yi0-yj0)*(yi0-yj0);
    const float d201 = (xi0-xj1)*(xi0-xj1) + (yi0-yj1)*(yi0-yj1);
    const float d210 = (xi1-xj0)*(xi1-xj0) + (yi1-yj0)*(yi1-yj0);
    const float d211 = (xi1-xj1)*(xi1-xj1) + (yi1-yj1)*(yi1-yj1);
    const float td00 = (d200 > 0.f) ? sqrtf(d200) : 0.f;
    const float td01 = (d201 > 0.f) ? sqrtf(d201) : 0.f;
    const float td10 = (d210 > 0.f) ? sqrtf(d210) : 0.f;
    const float td11 = (d211 > 0.f) ? sqrtf(d211) : 0.f;

    const int i0 = it * 32 + ti, i1 = i0 + 16;
    const int j0 = jt * 32 + tj, j1 = j0 + 16;
    out[((b * Kn) + i0) * Kn + j0] = sd00;
    out[((b * Kn) + i0) * Kn + j1] = sd01;
    out[((b * Kn) + i1) * Kn + j0] = sd10;
    out[((b * Kn) + i1) * Kn + j1] = sd11;

    // deterministic block reduce of squared error (4 outputs)
    float v = (sd00 - td00) * (sd00 - td00) + (sd01 - td01) * (sd01 - td01)
            + (sd10 - td10) * (sd10 - td10) + (sd11 - td11) * (sd11 - td11);
#pragma unroll
    for (int off = 32; off > 0; off >>= 1) v += __shfl_down(v, off);
    if ((tid & 63) == 0) wsum[tid >> 6] = v;
    __syncthreads();
    if (tid == 0) {
        const int bid = (b * gridDim.y + it) * gridDim.x + jt;
        partials[bid] = (wsum[0] + wsum[1]) + (wsum[2] + wsum[3]);
    }
}

// ---------------- Kernel C: final loss reduction (deterministic order) ----------------
__global__ __launch_bounds__(256) void kC(const float* __restrict__ partials,
                                          float* __restrict__ loss_out) {
    __shared__ float s[256];
    const int tid = threadIdx.x;
    const float4* p4 = (const float4*)partials;        // NBLK/4 = 256 float4
    const float4 x = p4[tid];
    s[tid] = (x.x + x.y) + (x.z + x.w);
    __syncthreads();
    for (int off = 128; off > 0; off >>= 1) {
        if (tid < off) s[tid] += s[tid + off];
        __syncthreads();
    }
    if (tid == 0)
        loss_out[0] = s[0] * (1.0f / (float)(Bn * Kn * Kn));
}

extern "C" void kernel_launch(void* const* d_in, const int* in_sizes, int n_in,
                              void* d_out, int out_size, void* d_ws, size_t ws_size,
                              hipStream_t stream) {
    const float* particles = (const float*)d_in[0];
    const float* positions = (const float*)d_in[1];
    const float* W1        = (const float*)d_in[2];
    const float* b1        = (const float*)d_in[3];
    const float* W2        = (const float*)d_in[4];
    const float* b2        = (const float*)d_in[5];

    float* out = (float*)d_out;                       // [B*K*K] sd, then [1] loss
    float* ws  = (float*)d_ws;
    float* hi       = ws;                             // B*K*H floats
    float* hj       = ws + Bn * Kn * Hn;
    float* partials = ws + 2 * Bn * Kn * Hn;          // NBLK floats

    kA<<<dim3((Bn * Kn) / ROWS_A), dim3(256), 0, stream>>>(particles, W1, b1, hi, hj);
    kB<<<dim3(Kn / 32, Kn / 32, Bn), dim3(256), 0, stream>>>(hi, hj, positions, W2, b2,
                                                             out, partials);
    kC<<<dim3(1), dim3(256), 0, stream>>>(partials, out + (size_t)Bn * Kn * Kn);
}

// Round 14
// 28.320 us; speedup vs baseline: 1.1571x; 1.1571x over previous
//
#include <hip/hip_runtime.h>
#include <hip/hip_bf16.h>
#include <math.h>

// Problem: B=16, K=256, D=128, H=64
//   hi[b,k,h] = particles[b,k,:] @ W1[:D, h] + b1[h]
//   hj[b,k,h] = particles[b,k,:] @ W1[D:, h]
//   sd[b,i,j] = sum_h gelu(hi[b,i,h] + hj[b,j,h]) * W2[h] + b2
//   loss = mean((sd - true_dist)^2)
//
// Measured lessons:
//  R7:  per-thread device fences (threadfence storm) = +90us. Loss stays kernel kC.
//  R10: v_pk_*_f32 = same FLOP rate as scalar (1 fma/lane/cyc). Only op count matters.
//  R13: v_rcp_f32 occupies the VALU ~8cyc (quarter-rate, NOT a parallel pipe) ->
//       magic+NR rcp (9 ops, 18cyc) beats hybrid (20cyc). kA was DS-pipe-bound
//       (3 DS per 8 fma at 1 wave/SIMD): fix = wave-uniform particle reads (SMEM
//       broadcast) + coalesced global W1 -> ZERO LDS in kA.

#define Bn 16
#define Kn 256
#define Dn 128
#define Hn 64
#define NBLK 1024    // kB grid: 8 x 8 x 16

// gelu(x) ~= x * sigmoid(1.702 x); Schraudolph exp2 bits + magic-rcp + 1 NR.
// 9 VALU ops per element incl. caller's x-add and the acc fma (18 SIMD-cyc).
__device__ __forceinline__ void gelu_acc(float x, float w, float& acc) {
    float u  = fmaf(x, -20598733.0f, 1064987473.0f);   // 2^(-2.4555x) bits
    int   iu = (int)u;                                 // u in (0, 2^31): |x| < 45
    float e  = __builtin_bit_cast(float, iu);
    float d  = e + 1.0f;
    int   ir = 0x7EF311C3 - __builtin_bit_cast(int, d);
    float r0 = __builtin_bit_cast(float, ir);
    float r  = r0 * fmaf(-d, r0, 2.0f);                // 1/d, ~0.2% rel
    acc = fmaf(x * r, w, acc);
}

// ---------------- Kernel A: hi/hj precompute, LDS-free ----------------
// 256 blocks x 512 threads. Block = 16 rows; wave w (=tid>>6) owns rows
// {16*blk + 2w, +1}; lane = h. Particle reads are wave-uniform -> SMEM
// broadcast; W1 reads coalesced 256B/wave (L2-resident). 4 fma/thread/d.
// FP order per (row,h): fmaf chain over ascending d == previous kernels.
__global__ __launch_bounds__(512) void kA(const float* __restrict__ particles,
                                          const float* __restrict__ W1,
                                          const float* __restrict__ b1,
                                          float* __restrict__ hi,
                                          float* __restrict__ hj) {
    const int tid = threadIdx.x;
    const int hg  = tid & 63;
    const int rg  = __builtin_amdgcn_readfirstlane(tid >> 6);  // 0..7, wave-uniform
    const int row = blockIdx.x * 16 + rg * 2;

    const float* __restrict__ p0 = particles + (size_t)row * Dn;
    const float* __restrict__ p1 = p0 + Dn;
    const float* __restrict__ wa = W1 + hg;             // W1[d*Hn + hg], d in [0,128)
    const float* __restrict__ wb = W1 + Dn * Hn + hg;   // second half

    float ai0 = 0.f, ai1 = 0.f, aj0 = 0.f, aj1 = 0.f;
#pragma unroll 8
    for (int d = 0; d < Dn; ++d) {
        const float pa = p0[d];          // wave-uniform -> s_load broadcast
        const float pb = p1[d];
        const float va = wa[(size_t)d * Hn];   // coalesced across lanes
        const float vb = wb[(size_t)d * Hn];
        ai0 = fmaf(pa, va, ai0); ai1 = fmaf(pb, va, ai1);
        aj0 = fmaf(pa, vb, aj0); aj1 = fmaf(pb, vb, aj1);
    }
    const float bh = b1[hg];
    hi[(size_t)row * Hn + hg]       = ai0 + bh;
    hi[(size_t)(row + 1) * Hn + hg] = ai1 + bh;
    hj[(size_t)row * Hn + hg]       = aj0;
    hj[(size_t)(row + 1) * Hn + hg] = aj1;
}

// ---------------- Kernel B: 32x32 tile, 4 outputs/thread (R11, measured-good) ----------------
// grid (K/32, K/32, B) = (8,8,16), 256 threads. Thread (ti=tid>>4, tj=tid&15)
// computes (i0,j0) (i0,j1) (i1,j0) (i1,j1), i1=i0+16, j1=j0+16.
__global__ __launch_bounds__(256) void kB(const float* __restrict__ hi,
                                          const float* __restrict__ hj,
                                          const float* __restrict__ positions,
                                          const float* __restrict__ W2,
                                          const float* __restrict__ b2,
                                          float* __restrict__ out,
                                          float* __restrict__ partials) {
    __shared__ __align__(16) float shi[32][68];
    __shared__ __align__(16) float shj[32][68];
    __shared__ __align__(16) float w2s[Hn];
    __shared__ float pix[32], piy[32], pjx[32], pjy[32];
    __shared__ float wsum[4];

    const int jt = blockIdx.x, it = blockIdx.y, b = blockIdx.z;
    const int tid = threadIdx.x;
    const int bi = b * Kn + it * 32;
    const int bj = b * Kn + jt * 32;

    // stage: 512 float4 each for shi/shj (2 per thread)
    for (int idx = tid; idx < 512; idx += 256) {
        const int rr = idx >> 4, c4 = (idx & 15) * 4;
        *(float4*)&shi[rr][c4] = *(const float4*)&hi[(bi + rr) * Hn + c4];
        *(float4*)&shj[rr][c4] = *(const float4*)&hj[(bj + rr) * Hn + c4];
    }
    if (tid < Hn / 4)
        ((float4*)w2s)[tid] = ((const float4*)W2)[tid];
    if (tid < 32) {
        pix[tid] = positions[(bi + tid) * 2 + 0];
        piy[tid] = positions[(bi + tid) * 2 + 1];
        pjx[tid] = positions[(bj + tid) * 2 + 0];
        pjy[tid] = positions[(bj + tid) * 2 + 1];
    }
    const float bb = b2[0];
    __syncthreads();

    const int ti = tid >> 4, tj = tid & 15;

    float acc00 = 0.f, acc01 = 0.f, acc10 = 0.f, acc11 = 0.f;
#pragma unroll
    for (int h = 0; h < Hn; h += 4) {
        const float4 a0 = *(const float4*)&shi[ti][h];
        const float4 a1 = *(const float4*)&shi[ti + 16][h];
        const float4 c0 = *(const float4*)&shj[tj][h];
        const float4 c1 = *(const float4*)&shj[tj + 16][h];
        const float4 w  = *(const float4*)&w2s[h];
        gelu_acc(a0.x + c0.x, w.x, acc00); gelu_acc(a0.y + c0.y, w.y, acc00);
        gelu_acc(a0.z + c0.z, w.z, acc00); gelu_acc(a0.w + c0.w, w.w, acc00);
        gelu_acc(a0.x + c1.x, w.x, acc01); gelu_acc(a0.y + c1.y, w.y, acc01);
        gelu_acc(a0.z + c1.z, w.z, acc01); gelu_acc(a0.w + c1.w, w.w, acc01);
        gelu_acc(a1.x + c0.x, w.x, acc10); gelu_acc(a1.y + c0.y, w.y, acc10);
        gelu_acc(a1.z + c0.z, w.z, acc10); gelu_acc(a1.w + c0.w, w.w, acc10);
        gelu_acc(a1.x + c1.x, w.x, acc11); gelu_acc(a1.y + c1.y, w.y, acc11);
        gelu_acc(a1.z + c1.z, w.z, acc11); gelu_acc(a1.w + c1.w, w.w, acc11);
    }
    const float sd00 = acc00 + bb, sd01 = acc01 + bb;
    const float sd10 = acc10 + bb, sd11 = acc11 + bb;

    const float xi0 = pix[ti], yi0 = piy[ti], xi1 = pix[ti + 16], yi1 = piy[ti + 16];
    const float xj0 = pjx[tj], yj0 = pjy[tj], xj1 = pjx[tj + 16], yj1 = pjy[tj + 16];
    const float d200 = (xi0-xj0)*(xi0-xj0) + (yi0-yj0)*(yi0-yj0);
    const float d201 = (xi0-xj1)*(xi0-xj1) + (yi0-yj1)*(yi0-yj1);
    const float d210 = (xi1-xj0)*(xi1-xj0) + (yi1-yj0)*(yi1-yj0);
    const float d211 = (xi1-xj1)*(xi1-xj1) + (yi1-yj1)*(yi1-yj1);
    const float td00 = (d200 > 0.f) ? sqrtf(d200) : 0.f;
    const float td01 = (d201 > 0.f) ? sqrtf(d201) : 0.f;
    const float td10 = (d210 > 0.f) ? sqrtf(d210) : 0.f;
    const float td11 = (d211 > 0.f) ? sqrtf(d211) : 0.f;

    const int i0 = it * 32 + ti, i1 = i0 + 16;
    const int j0 = jt * 32 + tj, j1 = j0 + 16;
    out[((b * Kn) + i0) * Kn + j0] = sd00;
    out[((b * Kn) + i0) * Kn + j1] = sd01;
    out[((b * Kn) + i1) * Kn + j0] = sd10;
    out[((b * Kn) + i1) * Kn + j1] = sd11;

    // deterministic block reduce of squared error (4 outputs)
    float v = (sd00 - td00) * (sd00 - td00) + (sd01 - td01) * (sd01 - td01)
            + (sd10 - td10) * (sd10 - td10) + (sd11 - td11) * (sd11 - td11);
#pragma unroll
    for (int off = 32; off > 0; off >>= 1) v += __shfl_down(v, off);
    if ((tid & 63) == 0) wsum[tid >> 6] = v;
    __syncthreads();
    if (tid == 0) {
        const int bid = (b * gridDim.y + it) * gridDim.x + jt;
        partials[bid] = (wsum[0] + wsum[1]) + (wsum[2] + wsum[3]);
    }
}

// ---------------- Kernel C: final loss reduction (deterministic order) ----------------
__global__ __launch_bounds__(256) void kC(const float* __restrict__ partials,
                                          float* __restrict__ loss_out) {
    __shared__ float s[256];
    const int tid = threadIdx.x;
    const float4* p4 = (const float4*)partials;        // NBLK/4 = 256 float4
    const float4 x = p4[tid];
    s[tid] = (x.x + x.y) + (x.z + x.w);
    __syncthreads();
    for (int off = 128; off > 0; off >>= 1) {
        if (tid < off) s[tid] += s[tid + off];
        __syncthreads();
    }
    if (tid == 0)
        loss_out[0] = s[0] * (1.0f / (float)(Bn * Kn * Kn));
}

extern "C" void kernel_launch(void* const* d_in, const int* in_sizes, int n_in,
                              void* d_out, int out_size, void* d_ws, size_t ws_size,
                              hipStream_t stream) {
    const float* particles = (const float*)d_in[0];
    const float* positions = (const float*)d_in[1];
    const float* W1        = (const float*)d_in[2];
    const float* b1        = (const float*)d_in[3];
    const float* W2        = (const float*)d_in[4];
    const float* b2        = (const float*)d_in[5];

    float* out = (float*)d_out;                       // [B*K*K] sd, then [1] loss
    float* ws  = (float*)d_ws;
    float* hi       = ws;                             // B*K*H floats
    float* hj       = ws + Bn * Kn * Hn;
    float* partials = ws + 2 * Bn * Kn * Hn;          // NBLK floats

    kA<<<dim3((Bn * Kn) / 16), dim3(512), 0, stream>>>(particles, W1, b1, hi, hj);
    kB<<<dim3(Kn / 32, Kn / 32, Bn), dim3(256), 0, stream>>>(hi, hj, positions, W2, b2,
                                                             out, partials);
    kC<<<dim3(1), dim3(256), 0, stream>>>(partials, out + (size_t)Bn * Kn * Kn);
}